// Round 1
// baseline (165.725 us; speedup 1.0000x reference)
//
#include <hip/hip_runtime.h>
#include <hip/hip_bf16.h>

#define NROWS 2048
#define MCOLS 2048
#define DDIM  64
#define TILE  64

// ---- sortable-uint encoding for float atomicMax (works for all finite floats,
//      and memset(0) is the identity: 0 sorts below -inf's encoding) ----
__device__ __forceinline__ unsigned f2sort(float f) {
  unsigned u = __float_as_uint(f);
  return (u & 0x80000000u) ? ~u : (u | 0x80000000u);
}
__device__ __forceinline__ float sort2f(unsigned u) {
  return (u & 0x80000000u) ? __uint_as_float(u ^ 0x80000000u)
                           : __uint_as_float(~u);
}

// Computes sv[a][b] = s[bi*64 + (t>>4)*4 + a][bj*64 + (t&15)*4 + b]
// for this thread, via LDS-transposed tiles. s = -sum_d |x-y|.
__device__ __forceinline__ void compute_tile_s(
    const float* __restrict__ zx, const float* __restrict__ zy,
    int bi, int bj, float sv[4][4])
{
  __shared__ float sX[DDIM][TILE];  // [d][i]
  __shared__ float sY[DDIM][TILE];  // [d][j]
  int t = threadIdx.x;
  int r  = t & 63;            // row within tile (staging)
  int d0 = (t >> 6) << 2;     // 0,4,8,12 (per wave)
  const float* zxp = zx + (size_t)(bi * TILE + r) * DDIM;
  const float* zyp = zy + (size_t)(bj * TILE + r) * DDIM;
#pragma unroll
  for (int q = 0; q < 4; ++q) {
    int d = d0 + 16 * q;
    float4 xv = *(const float4*)(zxp + d);
    float4 yv = *(const float4*)(zyp + d);
    sX[d + 0][r] = xv.x; sX[d + 1][r] = xv.y;
    sX[d + 2][r] = xv.z; sX[d + 3][r] = xv.w;
    sY[d + 0][r] = yv.x; sY[d + 1][r] = yv.y;
    sY[d + 2][r] = yv.z; sY[d + 3][r] = yv.w;
  }
  __syncthreads();
  int i0 = (t >> 4) << 2;
  int j0 = (t & 15) << 2;
  float acc[4][4] = {{0.f}};
#pragma unroll 8
  for (int d = 0; d < DDIM; ++d) {
    float4 xv = *(const float4*)&sX[d][i0];
    float4 yv = *(const float4*)&sY[d][j0];
    float xr[4] = {xv.x, xv.y, xv.z, xv.w};
    float yc[4] = {yv.x, yv.y, yv.z, yv.w};
#pragma unroll
    for (int a = 0; a < 4; ++a)
#pragma unroll
      for (int b = 0; b < 4; ++b)
        acc[a][b] += fabsf(xr[a] - yc[b]);
  }
#pragma unroll
  for (int a = 0; a < 4; ++a)
#pragma unroll
    for (int b = 0; b < 4; ++b)
      sv[a][b] = -acc[a][b];
}

__device__ __forceinline__ void load_tile_s(
    const float* __restrict__ s_in, int bi, int bj, float sv[4][4])
{
  int t = threadIdx.x;
  int i0 = (t >> 4) << 2;
  int j0 = (t & 15) << 2;
  const float* base = s_in + (size_t)(bi * TILE + i0) * MCOLS + bj * TILE + j0;
#pragma unroll
  for (int a = 0; a < 4; ++a) {
    float4 v = *(const float4*)(base + (size_t)a * MCOLS);
    sv[a][0] = v.x; sv[a][1] = v.y; sv[a][2] = v.z; sv[a][3] = v.w;
  }
}

template<bool STORE>
__global__ __launch_bounds__(256) void k1_dist_max(
    const float* __restrict__ zx, const float* __restrict__ zy,
    float* __restrict__ s_out,
    unsigned* __restrict__ rowmax, unsigned* __restrict__ colmax)
{
  int bi = blockIdx.y, bj = blockIdx.x;
  float sv[4][4];
  compute_tile_s(zx, zy, bi, bj, sv);
  int t  = threadIdx.x;
  int i0 = (t >> 4) << 2, j0 = (t & 15) << 2;
  if (STORE) {
#pragma unroll
    for (int a = 0; a < 4; ++a) {
      float4 v = make_float4(sv[a][0], sv[a][1], sv[a][2], sv[a][3]);
      *(float4*)(s_out + (size_t)(bi * TILE + i0 + a) * MCOLS + bj * TILE + j0) = v;
    }
  }
  float rm[4], cm[4];
#pragma unroll
  for (int a = 0; a < 4; ++a)
    rm[a] = fmaxf(fmaxf(sv[a][0], sv[a][1]), fmaxf(sv[a][2], sv[a][3]));
#pragma unroll
  for (int b = 0; b < 4; ++b)
    cm[b] = fmaxf(fmaxf(sv[0][b], sv[1][b]), fmaxf(sv[2][b], sv[3][b]));
  // row-reduce across the 16 tj lanes (bits 0..3 of lane id)
#pragma unroll
  for (int off = 1; off <= 8; off <<= 1)
#pragma unroll
    for (int a = 0; a < 4; ++a)
      rm[a] = fmaxf(rm[a], __shfl_xor(rm[a], off));
  int lid = t & 63;
  if ((lid & 15) == 0) {
#pragma unroll
    for (int a = 0; a < 4; ++a)
      atomicMax(&rowmax[bi * TILE + i0 + a], f2sort(rm[a]));
  }
  // col-reduce across ti lanes within the wave (bits 4..5 of lane id)
#pragma unroll
  for (int off = 16; off <= 32; off <<= 1)
#pragma unroll
    for (int b = 0; b < 4; ++b)
      cm[b] = fmaxf(cm[b], __shfl_xor(cm[b], off));
  if ((lid & 48) == 0) {
#pragma unroll
    for (int b = 0; b < 4; ++b)
      atomicMax(&colmax[bj * TILE + j0 + b], f2sort(cm[b]));
  }
}

template<bool STORE>
__global__ __launch_bounds__(256) void k2_sums(
    const float* __restrict__ zx, const float* __restrict__ zy,
    const float* __restrict__ s_in,
    const unsigned* __restrict__ rowmax, const unsigned* __restrict__ colmax,
    float* __restrict__ rowsum, float* __restrict__ colsum)
{
  int bi = blockIdx.y, bj = blockIdx.x;
  float sv[4][4];
  if constexpr (STORE) load_tile_s(s_in, bi, bj, sv);
  else                 compute_tile_s(zx, zy, bi, bj, sv);
  int t  = threadIdx.x;
  int i0 = (t >> 4) << 2, j0 = (t & 15) << 2;
  float rm[4], cm[4];
#pragma unroll
  for (int a = 0; a < 4; ++a) rm[a] = sort2f(rowmax[bi * TILE + i0 + a]);
#pragma unroll
  for (int b = 0; b < 4; ++b) cm[b] = sort2f(colmax[bj * TILE + j0 + b]);
  float rs[4] = {0.f, 0.f, 0.f, 0.f};
  float cs[4] = {0.f, 0.f, 0.f, 0.f};
#pragma unroll
  for (int a = 0; a < 4; ++a)
#pragma unroll
    for (int b = 0; b < 4; ++b) {
      rs[a] += __expf(sv[a][b] - rm[a]);
      cs[b] += __expf(sv[a][b] - cm[b]);
    }
#pragma unroll
  for (int off = 1; off <= 8; off <<= 1)
#pragma unroll
    for (int a = 0; a < 4; ++a)
      rs[a] += __shfl_xor(rs[a], off);
  int lid = t & 63;
  if ((lid & 15) == 0) {
#pragma unroll
    for (int a = 0; a < 4; ++a)
      atomicAdd(&rowsum[bi * TILE + i0 + a], rs[a]);
  }
#pragma unroll
  for (int off = 16; off <= 32; off <<= 1)
#pragma unroll
    for (int b = 0; b < 4; ++b)
      cs[b] += __shfl_xor(cs[b], off);
  if ((lid & 48) == 0) {
#pragma unroll
    for (int b = 0; b < 4; ++b)
      atomicAdd(&colsum[bj * TILE + j0 + b], cs[b]);
  }
}

template<bool STORE>
__global__ __launch_bounds__(256) void k3_final(
    const float* __restrict__ zx, const float* __restrict__ zy,
    const float* __restrict__ s_in,
    const unsigned* __restrict__ rowmax, const unsigned* __restrict__ colmax,
    const float* __restrict__ rowsum, const float* __restrict__ colsum,
    float* __restrict__ accum /* [0]=num, [1]=den */)
{
  int bi = blockIdx.y, bj = blockIdx.x;
  float sv[4][4];
  if constexpr (STORE) load_tile_s(s_in, bi, bj, sv);
  else                 compute_tile_s(zx, zy, bi, bj, sv);
  int t  = threadIdx.x;
  int i0 = (t >> 4) << 2, j0 = (t & 15) << 2;
  float rm[4], cm[4], rinv[4], cinv[4];
#pragma unroll
  for (int a = 0; a < 4; ++a) {
    rm[a]   = sort2f(rowmax[bi * TILE + i0 + a]);
    rinv[a] = 1.f / rowsum[bi * TILE + i0 + a];
  }
#pragma unroll
  for (int b = 0; b < 4; ++b) {
    cm[b]   = sort2f(colmax[bj * TILE + j0 + b]);
    cinv[b] = 1.f / colsum[bj * TILE + j0 + b];
  }
  float pn = 0.f, pd = 0.f;
#pragma unroll
  for (int a = 0; a < 4; ++a)
#pragma unroll
    for (int b = 0; b < 4; ++b) {
      float av = __expf(sv[a][b] - rm[a]) * rinv[a];
      float bv = __expf(sv[a][b] - cm[b]) * cinv[b];
      float w  = av + bv - av * bv;
      pn += w * sv[a][b];
      pd += w;
    }
#pragma unroll
  for (int off = 1; off <= 32; off <<= 1) {
    pn += __shfl_xor(pn, off);
    pd += __shfl_xor(pd, off);
  }
  if ((t & 63) == 0) {
    atomicAdd(&accum[0], pn);
    atomicAdd(&accum[1], pd);
  }
}

__global__ void k4_out(const float* __restrict__ accum, float* __restrict__ out) {
  out[0] = accum[0] / accum[1];
}

extern "C" void kernel_launch(void* const* d_in, const int* in_sizes, int n_in,
                              void* d_out, int out_size, void* d_ws, size_t ws_size,
                              hipStream_t stream)
{
  const float* zx = (const float*)d_in[0];
  const float* zy = (const float*)d_in[1];
  float* out = (float*)d_out;

  char* ws = (char*)d_ws;
  unsigned* rowmax = (unsigned*)(ws);              // 2048 u32
  unsigned* colmax = (unsigned*)(ws + 8192);       // 2048 u32
  float*    rowsum = (float*)   (ws + 16384);      // 2048 f32
  float*    colsum = (float*)   (ws + 24576);      // 2048 f32
  float*    accum  = (float*)   (ws + 32768);      // 2 f32
  float*    s_buf  = (float*)   (ws + 65536);      // 2048*2048 f32 (16 MiB)
  const size_t S_BYTES = (size_t)NROWS * MCOLS * sizeof(float);
  const bool store = ws_size >= (size_t)65536 + S_BYTES;

  // zero the stats region every call (harness does not re-poison between replays)
  hipMemsetAsync(d_ws, 0, 32768 + 64, stream);

  dim3 grid(MCOLS / TILE, NROWS / TILE);
  dim3 block(256);
  if (store) {
    k1_dist_max<true ><<<grid, block, 0, stream>>>(zx, zy, s_buf, rowmax, colmax);
    k2_sums   <true ><<<grid, block, 0, stream>>>(zx, zy, s_buf, rowmax, colmax, rowsum, colsum);
    k3_final  <true ><<<grid, block, 0, stream>>>(zx, zy, s_buf, rowmax, colmax, rowsum, colsum, accum);
  } else {
    k1_dist_max<false><<<grid, block, 0, stream>>>(zx, zy, s_buf, rowmax, colmax);
    k2_sums   <false><<<grid, block, 0, stream>>>(zx, zy, s_buf, rowmax, colmax, rowsum, colsum);
    k3_final  <false><<<grid, block, 0, stream>>>(zx, zy, s_buf, rowmax, colmax, rowsum, colsum, accum);
  }
  k4_out<<<dim3(1), dim3(1), 0, stream>>>(accum, out);
}

// Round 2
// 46.730 us; speedup vs baseline: 3.5464x; 3.5464x over previous
//
#include <hip/hip_runtime.h>

#define NROWS 2048
#define MCOLS 2048
#define DDIM  64
#define TILE  64
#define NTI   (NROWS / TILE)   // 32 tile-rows
#define NTJ   (MCOLS / TILE)   // 32 tile-cols

// Computes sv[a][b] = s[bi*64 + (t>>4)*4 + a][bj*64 + (t&15)*4 + b]
// for this thread, via LDS-transposed tiles. s = -sum_d |x-y|.
__device__ __forceinline__ void compute_tile_s(
    const float* __restrict__ zx, const float* __restrict__ zy,
    int bi, int bj, float sv[4][4])
{
  __shared__ float sX[DDIM][TILE];  // [d][i]
  __shared__ float sY[DDIM][TILE];  // [d][j]
  int t = threadIdx.x;
  int r  = t & 63;            // row within tile (staging)
  int d0 = (t >> 6) << 2;     // 0,4,8,12 (per wave)
  const float* zxp = zx + (size_t)(bi * TILE + r) * DDIM;
  const float* zyp = zy + (size_t)(bj * TILE + r) * DDIM;
#pragma unroll
  for (int q = 0; q < 4; ++q) {
    int d = d0 + 16 * q;
    float4 xv = *(const float4*)(zxp + d);
    float4 yv = *(const float4*)(zyp + d);
    sX[d + 0][r] = xv.x; sX[d + 1][r] = xv.y;
    sX[d + 2][r] = xv.z; sX[d + 3][r] = xv.w;
    sY[d + 0][r] = yv.x; sY[d + 1][r] = yv.y;
    sY[d + 2][r] = yv.z; sY[d + 3][r] = yv.w;
  }
  __syncthreads();
  int i0 = (t >> 4) << 2;
  int j0 = (t & 15) << 2;
  float acc[4][4] = {{0.f}};
#pragma unroll 8
  for (int d = 0; d < DDIM; ++d) {
    float4 xv = *(const float4*)&sX[d][i0];
    float4 yv = *(const float4*)&sY[d][j0];
    float xr[4] = {xv.x, xv.y, xv.z, xv.w};
    float yc[4] = {yv.x, yv.y, yv.z, yv.w};
#pragma unroll
    for (int a = 0; a < 4; ++a)
#pragma unroll
      for (int b = 0; b < 4; ++b)
        acc[a][b] += fabsf(xr[a] - yc[b]);
  }
#pragma unroll
  for (int a = 0; a < 4; ++a)
#pragma unroll
    for (int b = 0; b < 4; ++b)
      sv[a][b] = -acc[a][b];
}

__device__ __forceinline__ void load_tile_s(
    const float* __restrict__ s_in, int bi, int bj, float sv[4][4])
{
  int t = threadIdx.x;
  int i0 = (t >> 4) << 2;
  int j0 = (t & 15) << 2;
  const float* base = s_in + (size_t)(bi * TILE + i0) * MCOLS + bj * TILE + j0;
#pragma unroll
  for (int a = 0; a < 4; ++a) {
    float4 v = *(const float4*)(base + (size_t)a * MCOLS);
    sv[a][0] = v.x; sv[a][1] = v.y; sv[a][2] = v.z; sv[a][3] = v.w;
  }
}

// Pass 1: compute s tile, store it, and emit per-tile (max, expsum) partials
// for both rows and cols. NO atomics: each block owns distinct slots.
//   rm_part/rs_part: [NTJ][NROWS]  (tile-col index major)
//   cm_part/cs_part: [NTI][MCOLS]  (tile-row index major)
template<bool STORE>
__global__ __launch_bounds__(256) void k1_stats(
    const float* __restrict__ zx, const float* __restrict__ zy,
    float* __restrict__ s_out,
    float* __restrict__ rm_part, float* __restrict__ rs_part,
    float* __restrict__ cm_part, float* __restrict__ cs_part)
{
  int bi = blockIdx.y, bj = blockIdx.x;
  float sv[4][4];
  compute_tile_s(zx, zy, bi, bj, sv);
  int t  = threadIdx.x;
  int lid = t & 63, wv = t >> 6;
  int i0 = (t >> 4) << 2, j0 = (t & 15) << 2;

  if (STORE) {
#pragma unroll
    for (int a = 0; a < 4; ++a) {
      float4 v = make_float4(sv[a][0], sv[a][1], sv[a][2], sv[a][3]);
      *(float4*)(s_out + (size_t)(bi * TILE + i0 + a) * MCOLS + bj * TILE + j0) = v;
    }
  }

  // ---- row stats: 16 lanes (bits 0..3) cover one tile-row ----
  float rm[4], es[4];
#pragma unroll
  for (int a = 0; a < 4; ++a)
    rm[a] = fmaxf(fmaxf(sv[a][0], sv[a][1]), fmaxf(sv[a][2], sv[a][3]));
#pragma unroll
  for (int off = 1; off <= 8; off <<= 1)
#pragma unroll
    for (int a = 0; a < 4; ++a)
      rm[a] = fmaxf(rm[a], __shfl_xor(rm[a], off));
#pragma unroll
  for (int a = 0; a < 4; ++a) {
    es[a] = __expf(sv[a][0] - rm[a]) + __expf(sv[a][1] - rm[a])
          + __expf(sv[a][2] - rm[a]) + __expf(sv[a][3] - rm[a]);
  }
#pragma unroll
  for (int off = 1; off <= 8; off <<= 1)
#pragma unroll
    for (int a = 0; a < 4; ++a)
      es[a] += __shfl_xor(es[a], off);
  if ((lid & 15) == 0) {
#pragma unroll
    for (int a = 0; a < 4; ++a) {
      int idx = bj * NROWS + bi * TILE + i0 + a;
      rm_part[idx] = rm[a];
      rs_part[idx] = es[a];
    }
  }

  // ---- col stats: bits 4..5 within wave, then LDS across 4 waves ----
  float cm[4], ce[4];
#pragma unroll
  for (int b = 0; b < 4; ++b)
    cm[b] = fmaxf(fmaxf(sv[0][b], sv[1][b]), fmaxf(sv[2][b], sv[3][b]));
#pragma unroll
  for (int off = 16; off <= 32; off <<= 1)
#pragma unroll
    for (int b = 0; b < 4; ++b)
      cm[b] = fmaxf(cm[b], __shfl_xor(cm[b], off));
#pragma unroll
  for (int b = 0; b < 4; ++b) {
    ce[b] = __expf(sv[0][b] - cm[b]) + __expf(sv[1][b] - cm[b])
          + __expf(sv[2][b] - cm[b]) + __expf(sv[3][b] - cm[b]);
  }
#pragma unroll
  for (int off = 16; off <= 32; off <<= 1)
#pragma unroll
    for (int b = 0; b < 4; ++b)
      ce[b] += __shfl_xor(ce[b], off);

  __shared__ float cmw[4][TILE];
  __shared__ float csw[4][TILE];
  if (lid < 16) {
#pragma unroll
    for (int b = 0; b < 4; ++b) {
      cmw[wv][lid * 4 + b] = cm[b];
      csw[wv][lid * 4 + b] = ce[b];
    }
  }
  __syncthreads();
  if (t < TILE) {
    int j = t;
    float M = fmaxf(fmaxf(cmw[0][j], cmw[1][j]), fmaxf(cmw[2][j], cmw[3][j]));
    float S = __expf(cmw[0][j] - M) * csw[0][j]
            + __expf(cmw[1][j] - M) * csw[1][j]
            + __expf(cmw[2][j] - M) * csw[2][j]
            + __expf(cmw[3][j] - M) * csw[3][j];
    int idx = bi * MCOLS + bj * TILE + j;
    cm_part[idx] = M;
    cs_part[idx] = S;
  }
}

// Pass 1b: reduce 32 tile-partials per row/col into global max + 1/sum.
__global__ __launch_bounds__(256) void kr_reduce(
    const float* __restrict__ rm_part, const float* __restrict__ rs_part,
    const float* __restrict__ cm_part, const float* __restrict__ cs_part,
    float* __restrict__ rowmax, float* __restrict__ rowinv,
    float* __restrict__ colmax, float* __restrict__ colinv)
{
  int g = blockIdx.x * 256 + threadIdx.x;
  if (g < NROWS) {
    int i = g;
    float M = -3.4e38f;
#pragma unroll 8
    for (int tj = 0; tj < NTJ; ++tj) M = fmaxf(M, rm_part[tj * NROWS + i]);
    float S = 0.f;
#pragma unroll 8
    for (int tj = 0; tj < NTJ; ++tj)
      S += __expf(rm_part[tj * NROWS + i] - M) * rs_part[tj * NROWS + i];
    rowmax[i] = M;
    rowinv[i] = 1.f / S;
  } else if (g < NROWS + MCOLS) {
    int j = g - NROWS;
    float M = -3.4e38f;
#pragma unroll 8
    for (int ti = 0; ti < NTI; ++ti) M = fmaxf(M, cm_part[ti * MCOLS + j]);
    float S = 0.f;
#pragma unroll 8
    for (int ti = 0; ti < NTI; ++ti)
      S += __expf(cm_part[ti * MCOLS + j] - M) * cs_part[ti * MCOLS + j];
    colmax[j] = M;
    colinv[j] = 1.f / S;
  }
}

// Pass 2: final combine. Per-wave partials, NO atomics.
template<bool STORE>
__global__ __launch_bounds__(256) void k3_final(
    const float* __restrict__ zx, const float* __restrict__ zy,
    const float* __restrict__ s_in,
    const float* __restrict__ rowmax, const float* __restrict__ rowinv,
    const float* __restrict__ colmax, const float* __restrict__ colinv,
    float* __restrict__ part /* [gridBlocks*4][2] */)
{
  int bi = blockIdx.y, bj = blockIdx.x;
  float sv[4][4];
  if constexpr (STORE) load_tile_s(s_in, bi, bj, sv);
  else                 compute_tile_s(zx, zy, bi, bj, sv);
  int t  = threadIdx.x;
  int i0 = (t >> 4) << 2, j0 = (t & 15) << 2;
  float rm[4], cm[4], rinv[4], cinv[4];
#pragma unroll
  for (int a = 0; a < 4; ++a) {
    rm[a]   = rowmax[bi * TILE + i0 + a];
    rinv[a] = rowinv[bi * TILE + i0 + a];
  }
#pragma unroll
  for (int b = 0; b < 4; ++b) {
    cm[b]   = colmax[bj * TILE + j0 + b];
    cinv[b] = colinv[bj * TILE + j0 + b];
  }
  float pn = 0.f, pd = 0.f;
#pragma unroll
  for (int a = 0; a < 4; ++a)
#pragma unroll
    for (int b = 0; b < 4; ++b) {
      float av = __expf(sv[a][b] - rm[a]) * rinv[a];
      float bv = __expf(sv[a][b] - cm[b]) * cinv[b];
      float w  = av + bv - av * bv;
      pn += w * sv[a][b];
      pd += w;
    }
#pragma unroll
  for (int off = 1; off <= 32; off <<= 1) {
    pn += __shfl_xor(pn, off);
    pd += __shfl_xor(pd, off);
  }
  if ((t & 63) == 0) {
    int w = (bi * NTJ + bj) * 4 + (t >> 6);
    part[w * 2 + 0] = pn;
    part[w * 2 + 1] = pd;
  }
}

// Pass 3: deterministic tree-reduce of 4096 per-wave partials, one block.
__global__ __launch_bounds__(256) void k4_out(
    const float* __restrict__ part, float* __restrict__ out)
{
  int t = threadIdx.x;
  float pn = 0.f, pd = 0.f;
  for (int k = t; k < NTI * NTJ * 4; k += 256) {
    pn += part[k * 2 + 0];
    pd += part[k * 2 + 1];
  }
#pragma unroll
  for (int off = 1; off <= 32; off <<= 1) {
    pn += __shfl_xor(pn, off);
    pd += __shfl_xor(pd, off);
  }
  __shared__ float red[8];
  if ((t & 63) == 0) { red[(t >> 6) * 2] = pn; red[(t >> 6) * 2 + 1] = pd; }
  __syncthreads();
  if (t == 0) {
    float n = red[0] + red[2] + red[4] + red[6];
    float d = red[1] + red[3] + red[5] + red[7];
    out[0] = n / d;
  }
}

extern "C" void kernel_launch(void* const* d_in, const int* in_sizes, int n_in,
                              void* d_out, int out_size, void* d_ws, size_t ws_size,
                              hipStream_t stream)
{
  const float* zx = (const float*)d_in[0];
  const float* zy = (const float*)d_in[1];
  float* out = (float*)d_out;

  char* ws = (char*)d_ws;
  // finals + partials (all fully overwritten every call; no memset needed)
  float* rowmax  = (float*)(ws + 0);         // 8 KB
  float* rowinv  = (float*)(ws + (8 << 10));
  float* colmax  = (float*)(ws + (16 << 10));
  float* colinv  = (float*)(ws + (24 << 10));
  float* part    = (float*)(ws + (32 << 10));   // 4096*2 f32 = 32 KB
  float* rm_part = (float*)(ws + (64 << 10));   // 32*2048 = 256 KB
  float* rs_part = (float*)(ws + (320 << 10));
  float* cm_part = (float*)(ws + (576 << 10));
  float* cs_part = (float*)(ws + (832 << 10));
  float* s_buf   = (float*)(ws + (1088 << 10)); // 16 MiB
  const size_t NEED = (size_t)(1088 << 10) + (size_t)NROWS * MCOLS * sizeof(float);
  const bool store = ws_size >= NEED;

  dim3 grid(NTJ, NTI);
  dim3 block(256);
  if (store) {
    k1_stats<true ><<<grid, block, 0, stream>>>(zx, zy, s_buf, rm_part, rs_part, cm_part, cs_part);
    kr_reduce<<<dim3(16), block, 0, stream>>>(rm_part, rs_part, cm_part, cs_part,
                                              rowmax, rowinv, colmax, colinv);
    k3_final<true ><<<grid, block, 0, stream>>>(zx, zy, s_buf, rowmax, rowinv, colmax, colinv, part);
  } else {
    k1_stats<false><<<grid, block, 0, stream>>>(zx, zy, s_buf, rm_part, rs_part, cm_part, cs_part);
    kr_reduce<<<dim3(16), block, 0, stream>>>(rm_part, rs_part, cm_part, cs_part,
                                              rowmax, rowinv, colmax, colinv);
    k3_final<false><<<grid, block, 0, stream>>>(zx, zy, s_buf, rowmax, rowinv, colmax, colinv, part);
  }
  k4_out<<<dim3(1), block, 0, stream>>>(part, out);
}